// Round 1
// baseline (725.549 us; speedup 1.0000x reference)
//
#include <hip/hip_runtime.h>

#define NCLASS 100

// Kernel 1: per-row argmax + per-block LDS histogram -> global counts.
__global__ __launch_bounds__(256) void argmax_hist_kernel(
    const float* __restrict__ logits,
    unsigned int* __restrict__ counts,
    int nrows)
{
    __shared__ unsigned int lhist[NCLASS];
    for (int i = threadIdx.x; i < NCLASS; i += blockDim.x) lhist[i] = 0u;
    __syncthreads();

    const int stride = gridDim.x * blockDim.x;
    for (int row = blockIdx.x * blockDim.x + threadIdx.x; row < nrows; row += stride) {
        const float4* p = reinterpret_cast<const float4*>(logits + (size_t)row * NCLASS);
        float best = -__builtin_huge_valf();
        int bidx = 0;
        #pragma unroll
        for (int k = 0; k < 25; ++k) {
            float4 v = p[k];
            // strict > keeps the FIRST occurrence of the max, matching jnp.argmax
            if (v.x > best) { best = v.x; bidx = 4 * k + 0; }
            if (v.y > best) { best = v.y; bidx = 4 * k + 1; }
            if (v.z > best) { best = v.z; bidx = 4 * k + 2; }
            if (v.w > best) { best = v.w; bidx = 4 * k + 3; }
        }
        atomicAdd(&lhist[bidx], 1u);
    }

    __syncthreads();
    for (int i = threadIdx.x; i < NCLASS; i += blockDim.x) {
        unsigned int c = lhist[i];
        if (c) atomicAdd(&counts[i], c);
    }
}

// Kernel 2: entropy from counts. Single block of 128 threads.
__global__ __launch_bounds__(128) void entropy_kernel(
    const unsigned int* __restrict__ counts,
    float* __restrict__ out,
    float invB)
{
    __shared__ float partial[128];
    const int t = threadIdx.x;
    float term = 0.0f;
    if (t < NCLASS) {
        float c = (float)counts[t];
        if (c > 0.0f) {
            float p = c * invB;
            term = p * (logf(p) * 1.4426950408889634f);  // p * log2(p)
        }
    }
    partial[t] = term;
    __syncthreads();
    #pragma unroll
    for (int s = 64; s > 0; s >>= 1) {
        if (t < s) partial[t] += partial[t + s];
        __syncthreads();
    }
    if (t == 0) out[0] = -partial[0];
}

extern "C" void kernel_launch(void* const* d_in, const int* in_sizes, int n_in,
                              void* d_out, int out_size, void* d_ws, size_t ws_size,
                              hipStream_t stream)
{
    const float* logits = (const float*)d_in[0];
    const int nrows = in_sizes[0] / NCLASS;

    unsigned int* counts = (unsigned int*)d_ws;

    // zero the count scratch (graph-capture-safe async memset)
    hipMemsetAsync(counts, 0, NCLASS * sizeof(unsigned int), stream);

    const int block = 256;
    const int grid = 2048;  // 8 rows per thread grid-stride
    argmax_hist_kernel<<<grid, block, 0, stream>>>(logits, counts, nrows);

    entropy_kernel<<<1, 128, 0, stream>>>(counts, (float*)d_out, 1.0f / (float)nrows);
}

// Round 2
// 328.841 us; speedup vs baseline: 2.2064x; 2.2064x over previous
//
#include <hip/hip_runtime.h>

#define NCLASS 100
#define TROWS 128      // rows per tile == threads per block
#define RSTRIDE 102    // padded LDS row stride in floats (8B-aligned float2 rows)

// Tile-staged argmax + per-block LDS histogram.
// Global reads are fully coalesced float4; per-row reduction reads LDS.
__global__ __launch_bounds__(128) void argmax_hist_kernel(
    const float4* __restrict__ g4,       // logits viewed as float4
    unsigned int* __restrict__ counts,
    int nrows)
{
    __shared__ float lds[TROWS * RSTRIDE];   // 52224 B
    __shared__ unsigned int lhist[NCLASS];

    const int tid = threadIdx.x;
    for (int i = tid; i < NCLASS; i += TROWS) lhist[i] = 0u;
    __syncthreads();

    const int ntiles = nrows / TROWS;        // nrows is a multiple of 128 here
    for (int tile = blockIdx.x; tile < ntiles; tile += gridDim.x) {
        const size_t base4 = (size_t)tile * (TROWS * 25);

        // ---- stage: 25 coalesced float4 loads per thread ----
        #pragma unroll
        for (int i = 0; i < 25; ++i) {
            const int f = i * TROWS + tid;           // consecutive lanes -> consecutive 16B
            float4 v = g4[base4 + f];
            const int r = f / 25;                    // row within tile
            const int c = f - r * 25;                // float4-chunk within row
            float2* w = reinterpret_cast<float2*>(&lds[r * RSTRIDE + c * 4]);
            w[0] = make_float2(v.x, v.y);
            w[1] = make_float2(v.z, v.w);
        }
        __syncthreads();

        // ---- reduce: thread t scans row t (column order => first-max tie-break) ----
        const float2* rp = reinterpret_cast<const float2*>(&lds[tid * RSTRIDE]);
        float best = -__builtin_huge_valf();
        int bidx = 0;
        #pragma unroll
        for (int j = 0; j < 50; ++j) {
            float2 v = rp[j];
            if (v.x > best) { best = v.x; bidx = 2 * j; }
            if (v.y > best) { best = v.y; bidx = 2 * j + 1; }
        }
        atomicAdd(&lhist[bidx], 1u);
        __syncthreads();   // protect lds before next tile's staging
    }

    // ---- flush histogram once per block ----
    for (int i = tid; i < NCLASS; i += TROWS) {
        unsigned int c = lhist[i];
        if (c) atomicAdd(&counts[i], c);
    }
}

// Entropy from counts. Single block of 128 threads.
__global__ __launch_bounds__(128) void entropy_kernel(
    const unsigned int* __restrict__ counts,
    float* __restrict__ out,
    float invB)
{
    __shared__ float partial[128];
    const int t = threadIdx.x;
    float term = 0.0f;
    if (t < NCLASS) {
        float c = (float)counts[t];
        if (c > 0.0f) {
            float p = c * invB;
            term = p * (logf(p) * 1.4426950408889634f);  // p * log2(p)
        }
    }
    partial[t] = term;
    __syncthreads();
    #pragma unroll
    for (int s = 64; s > 0; s >>= 1) {
        if (t < s) partial[t] += partial[t + s];
        __syncthreads();
    }
    if (t == 0) out[0] = -partial[0];
}

extern "C" void kernel_launch(void* const* d_in, const int* in_sizes, int n_in,
                              void* d_out, int out_size, void* d_ws, size_t ws_size,
                              hipStream_t stream)
{
    const float* logits = (const float*)d_in[0];
    const int nrows = in_sizes[0] / NCLASS;

    unsigned int* counts = (unsigned int*)d_ws;
    hipMemsetAsync(counts, 0, NCLASS * sizeof(unsigned int), stream);

    const int grid = 2048;   // 16 tiles per block grid-stride; 205K global atomics total
    argmax_hist_kernel<<<grid, TROWS, 0, stream>>>(
        (const float4*)logits, counts, nrows);

    entropy_kernel<<<1, 128, 0, stream>>>(counts, (float*)d_out, 1.0f / (float)nrows);
}

// Round 4
// 313.853 us; speedup vs baseline: 2.3117x; 1.0478x over previous
//
#include <hip/hip_runtime.h>

#define NCLASS 100
#define TROWS 64       // rows per tile == threads per block (1 wave)
#define RSTRIDE 102    // padded LDS row stride in floats (8B-aligned float2 rows)

typedef float fx4 __attribute__((ext_vector_type(4)));  // native vector: OK for nontemporal builtin

// Single-wave blocks; register-staged pipeline:
//   write stg(k) -> LDS ; issue loads(k+1) -> stg ; reduce LDS ; repeat
// so tile k+1's HBM latency hides under tile k's reduce.
__global__ __launch_bounds__(64) void argmax_hist_kernel(
    const fx4* __restrict__ g4,
    unsigned int* __restrict__ counts,
    int nrows)
{
    __shared__ float lds[TROWS * RSTRIDE];   // 26112 B -> 6 blocks/CU
    __shared__ unsigned int lhist[NCLASS];

    const int tid = threadIdx.x;
    #pragma unroll
    for (int i = tid; i < NCLASS; i += TROWS) lhist[i] = 0u;
    __syncthreads();   // single wave: ~free

    const int ntiles = nrows / TROWS;        // exact: 4194304 / 64
    fx4 stg[25];

    int tile = blockIdx.x;
    if (tile < ntiles) {                     // prologue: stage tile 0
        const size_t b4 = (size_t)tile * (TROWS * 25);
        #pragma unroll
        for (int i = 0; i < 25; ++i)
            stg[i] = __builtin_nontemporal_load(&g4[b4 + i * TROWS + tid]);
    }

    while (tile < ntiles) {
        // ---- regs -> LDS (compiler inserts vmcnt waits per register use) ----
        #pragma unroll
        for (int i = 0; i < 25; ++i) {
            const int f = i * TROWS + tid;
            const int r = f / 25;            // row within tile (magic-mul)
            const int c = f - r * 25;        // float4-chunk within row
            float2* w = reinterpret_cast<float2*>(&lds[r * RSTRIDE + c * 4]);
            w[0] = make_float2(stg[i].x, stg[i].y);
            w[1] = make_float2(stg[i].z, stg[i].w);
        }

        // ---- issue NEXT tile's loads now; they fly during the reduce ----
        const int ntile = tile + gridDim.x;
        if (ntile < ntiles) {
            const size_t b4 = (size_t)ntile * (TROWS * 25);
            #pragma unroll
            for (int i = 0; i < 25; ++i)
                stg[i] = __builtin_nontemporal_load(&g4[b4 + i * TROWS + tid]);
        }

        __syncthreads();   // orders LDS writes before reads (1 wave: cheap)

        // ---- reduce: thread t scans row t in column order (first-max tie-break) ----
        const float2* rp = reinterpret_cast<const float2*>(&lds[tid * RSTRIDE]);
        float best = -__builtin_huge_valf();
        int bidx = 0;
        #pragma unroll
        for (int j = 0; j < 50; ++j) {
            float2 v = rp[j];
            if (v.x > best) { best = v.x; bidx = 2 * j; }
            if (v.y > best) { best = v.y; bidx = 2 * j + 1; }
        }
        atomicAdd(&lhist[bidx], 1u);

        __syncthreads();   // reads done before next iteration's writes
        tile = ntile;
    }

    // ---- flush histogram once per block ----
    #pragma unroll
    for (int i = tid; i < NCLASS; i += TROWS) {
        unsigned int c = lhist[i];
        if (c) atomicAdd(&counts[i], c);
    }
}

// Entropy from counts. Single block of 128 threads.
__global__ __launch_bounds__(128) void entropy_kernel(
    const unsigned int* __restrict__ counts,
    float* __restrict__ out,
    float invB)
{
    __shared__ float partial[128];
    const int t = threadIdx.x;
    float term = 0.0f;
    if (t < NCLASS) {
        float c = (float)counts[t];
        if (c > 0.0f) {
            float p = c * invB;
            term = p * (logf(p) * 1.4426950408889634f);  // p * log2(p)
        }
    }
    partial[t] = term;
    __syncthreads();
    #pragma unroll
    for (int s = 64; s > 0; s >>= 1) {
        if (t < s) partial[t] += partial[t + s];
        __syncthreads();
    }
    if (t == 0) out[0] = -partial[0];
}

extern "C" void kernel_launch(void* const* d_in, const int* in_sizes, int n_in,
                              void* d_out, int out_size, void* d_ws, size_t ws_size,
                              hipStream_t stream)
{
    const float* logits = (const float*)d_in[0];
    const int nrows = in_sizes[0] / NCLASS;

    unsigned int* counts = (unsigned int*)d_ws;
    (void)hipMemsetAsync(counts, 0, NCLASS * sizeof(unsigned int), stream);

    const int grid = 4096;   // 16 tiles per block; 410K global atomics total
    argmax_hist_kernel<<<grid, TROWS, 0, stream>>>(
        (const fx4*)logits, counts, nrows);

    entropy_kernel<<<1, 128, 0, stream>>>(counts, (float*)d_out, 1.0f / (float)nrows);
}

// Round 5
// 310.072 us; speedup vs baseline: 2.3399x; 1.0122x over previous
//
#include <hip/hip_runtime.h>

#define NCLASS 100
#define TROWS 64       // rows per tile == threads per block (1 wave)
#define CHUNKS 25      // float4 chunks per row

typedef float fx4 __attribute__((ext_vector_type(4)));

// Register-reduce-then-LDS-transpose:
//   coalesced loads -> per-chunk (max,argcol) in regs -> 8B pairs through LDS
//   -> thread t scans row t's 25 pairs. LDS traffic = 1/4 of raw data.
__global__ __launch_bounds__(64) void argmax_hist_kernel(
    const fx4* __restrict__ g4,
    unsigned int* __restrict__ counts,
    int nrows)
{
    __shared__ float2 part[TROWS * CHUNKS];   // 12800 B -> 12 blocks/CU (3 waves/SIMD)
    __shared__ unsigned int lhist[NCLASS];

    const int tid = threadIdx.x;
    #pragma unroll
    for (int i = tid; i < NCLASS; i += TROWS) lhist[i] = 0u;
    __syncthreads();

    const int ntiles = nrows / TROWS;         // 65536 exactly
    fx4 stg[CHUNKS];

    int tile = blockIdx.x;
    if (tile < ntiles) {                      // prologue: stage tile 0
        const size_t b4 = (size_t)tile * (TROWS * CHUNKS);
        #pragma unroll
        for (int i = 0; i < CHUNKS; ++i)
            stg[i] = __builtin_nontemporal_load(&g4[b4 + i * TROWS + tid]);
    }

    while (tile < ntiles) {
        // ---- per-chunk argmax in regs; write (max, col) pairs linearly to LDS ----
        #pragma unroll
        for (int i = 0; i < CHUNKS; ++i) {
            const fx4 v = stg[i];
            float m = v.x; int ci = 0;
            if (v.y > m) { m = v.y; ci = 1; }     // element order => first max in chunk
            if (v.z > m) { m = v.z; ci = 2; }
            if (v.w > m) { m = v.w; ci = 3; }
            const int f = i * TROWS + tid;        // == row*25 + chunk  (linear!)
            const int c = f % CHUNKS;             // chunk index within row
            part[f] = make_float2(m, (float)(4 * c + ci));
        }

        // ---- issue NEXT tile's loads; they fly during the row-reduce ----
        const int ntile = tile + gridDim.x;
        if (ntile < ntiles) {
            const size_t b4 = (size_t)ntile * (TROWS * CHUNKS);
            #pragma unroll
            for (int i = 0; i < CHUNKS; ++i)
                stg[i] = __builtin_nontemporal_load(&g4[b4 + i * TROWS + tid]);
        }

        __syncthreads();   // order partial writes before row reads (1 wave: cheap)

        // ---- row-reduce: thread t scans row t's 25 pairs in chunk order ----
        const float2* rp = &part[tid * CHUNKS];
        float best = -__builtin_huge_valf();
        float bcol = 0.0f;
        #pragma unroll
        for (int j = 0; j < CHUNKS; ++j) {
            const float2 v = rp[j];
            if (v.x > best) { best = v.x; bcol = v.y; }   // strict > => first occurrence
        }
        atomicAdd(&lhist[(int)bcol], 1u);

        __syncthreads();   // reads done before next iteration's writes
        tile = ntile;
    }

    // ---- flush histogram once per block ----
    #pragma unroll
    for (int i = tid; i < NCLASS; i += TROWS) {
        unsigned int c = lhist[i];
        if (c) atomicAdd(&counts[i], c);
    }
}

// Entropy from counts. Single block of 128 threads.
__global__ __launch_bounds__(128) void entropy_kernel(
    const unsigned int* __restrict__ counts,
    float* __restrict__ out,
    float invB)
{
    __shared__ float partial[128];
    const int t = threadIdx.x;
    float term = 0.0f;
    if (t < NCLASS) {
        float c = (float)counts[t];
        if (c > 0.0f) {
            float p = c * invB;
            term = p * (logf(p) * 1.4426950408889634f);  // p * log2(p)
        }
    }
    partial[t] = term;
    __syncthreads();
    #pragma unroll
    for (int s = 64; s > 0; s >>= 1) {
        if (t < s) partial[t] += partial[t + s];
        __syncthreads();
    }
    if (t == 0) out[0] = -partial[0];
}

extern "C" void kernel_launch(void* const* d_in, const int* in_sizes, int n_in,
                              void* d_out, int out_size, void* d_ws, size_t ws_size,
                              hipStream_t stream)
{
    const float* logits = (const float*)d_in[0];
    const int nrows = in_sizes[0] / NCLASS;

    unsigned int* counts = (unsigned int*)d_ws;
    (void)hipMemsetAsync(counts, 0, NCLASS * sizeof(unsigned int), stream);

    const int grid = 4096;   // 16 tiles per block; 410K global atomics total
    argmax_hist_kernel<<<grid, TROWS, 0, stream>>>(
        (const fx4*)logits, counts, nrows);

    entropy_kernel<<<1, 128, 0, stream>>>(counts, (float*)d_out, 1.0f / (float)nrows);
}